// Round 1
// baseline (1777.286 us; speedup 1.0000x reference)
//
#include <hip/hip_runtime.h>
#include <hip/hip_bf16.h>
#include <math.h>

typedef __hip_bfloat16 bf16;

__device__ __forceinline__ int bitrev7(int x) {
  return ((x & 1) << 6) | ((x & 2) << 4) | ((x & 4) << 2) | (x & 8)
       | ((x & 16) >> 2) | ((x & 32) >> 4) | ((x & 64) >> 6);
}

// In-LDS 128-point complex FFT over 64 columns. lr/li layout: [slot*64 + col].
// sign = -1 forward exp(-i..), +1 inverse (unnormalized). 256 threads.
// Radix-2 DIF: natural-order input, bit-reversed-slot output (slot i holds freq bitrev7(i)).
// Ends with __syncthreads().
__device__ __forceinline__ void fft128(float* lr, float* li, float sign, int c, int wq) {
  const float base_ang = sign * (float)(2.0 * M_PI / 128.0);
  #pragma unroll
  for (int s = 0; s < 7; ++s) {
    int lh = 6 - s;
    int half = 1 << lh;
    __syncthreads();
    #pragma unroll
    for (int it = 0; it < 16; ++it) {
      int bf = wq + (it << 2);          // 0..63, disjoint across threads
      int j = bf & (half - 1);
      int blk = bf >> lh;
      int i1 = (blk << (lh + 1)) + j;
      int i2 = i1 + half;
      int k = j << s;                   // twiddle index 0..63
      float ar = lr[i1 * 64 + c], ai = li[i1 * 64 + c];
      float br = lr[i2 * 64 + c], bi = li[i2 * 64 + c];
      float sv, cv;
      __sincosf(base_ang * (float)k, &sv, &cv);   // W = (cv, sv) with sign folded in
      float dr = ar - br, di = ai - bi;
      lr[i1 * 64 + c] = ar + br;
      li[i1 * 64 + c] = ai + bi;
      lr[i2 * 64 + c] = dr * cv - di * sv;
      li[i2 * 64 + c] = dr * sv + di * cv;
    }
  }
  __syncthreads();
}

// ---- K1: forward rFFT along W. x[bh][w][c] -> Xr[bh][f<65][c], Xi padded [bh][128][c] (f<65 slots)
__global__ __launch_bounds__(256, 2) void k_fftw_fwd(
    const float* __restrict__ x, float* __restrict__ Xr, float* __restrict__ Xi) {
  __shared__ float lr[128 * 64], li[128 * 64];
  const int bh = blockIdx.x;
  const int c0 = blockIdx.y * 64;
  const int c = threadIdx.x & 63;
  const int wq = threadIdx.x >> 6;
  const float* xrow = x + (size_t)bh * (128 * 768) + c0 + c;
  #pragma unroll
  for (int it = 0; it < 32; ++it) {
    int w = wq + (it << 2);
    lr[w * 64 + c] = xrow[(size_t)w * 768];
    li[w * 64 + c] = 0.f;
  }
  fft128(lr, li, -1.f, c, wq);
  const float sc = 1.f / 128.f;   // full ortho forward scale (1/sqrt(H*W))
  #pragma unroll
  for (int it = 0; it < 32; ++it) {
    int slot = wq + (it << 2);
    int f = bitrev7(slot);
    if (f < 65) {
      Xr[((size_t)bh * 65 + f) * 768 + c0 + c]  = lr[slot * 64 + c] * sc;
      Xi[((size_t)bh * 128 + f) * 768 + c0 + c] = li[slot * 64 + c] * sc;
    }
  }
}

// ---- K2/K4: complex FFT along H, in-place per (b,wf) column. sign=-1 fwd, +1 inv.
__global__ __launch_bounds__(256, 2) void k_ffth(
    float* Xr, float* Xi, float sign, float scale) {
  __shared__ float lr[128 * 64], li[128 * 64];
  const int bw = blockIdx.x;            // b*65 + wf
  const int b = bw / 65, wf = bw % 65;
  const int c0 = blockIdx.y * 64;
  const int c = threadIdx.x & 63;
  const int wq = threadIdx.x >> 6;
  const size_t baser = ((size_t)b * 128 * 65 + wf) * 768 + c0 + c;    // + h*65*768
  const size_t basei = ((size_t)b * 128 * 128 + wf) * 768 + c0 + c;   // + h*128*768
  #pragma unroll
  for (int it = 0; it < 32; ++it) {
    int h = wq + (it << 2);
    lr[h * 64 + c] = Xr[baser + (size_t)h * (65 * 768)];
    li[h * 64 + c] = Xi[basei + (size_t)h * (128 * 768)];
  }
  fft128(lr, li, sign, c, wq);
  #pragma unroll
  for (int it = 0; it < 32; ++it) {
    int slot = wq + (it << 2);
    int hf = bitrev7(slot);
    Xr[baser + (size_t)hf * (65 * 768)]  = lr[slot * 64 + c] * scale;
    Xi[basei + (size_t)hf * (128 * 768)] = li[slot * 64 + c] * scale;
  }
}

// ---- K3: block-diagonal complex MLP, both layers fused. In-place on Xr/Xi.
// grid (520, 8): 64 positions x block n per workgroup. wave v handles out-ch [24v,24v+24).
__global__ __launch_bounds__(256, 2) void k_mlp(
    float* __restrict__ Xr, float* __restrict__ Xi,
    const float* __restrict__ w1, const float* __restrict__ b1,
    const float* __restrict__ w2, const float* __restrict__ b2) {
  __shared__ bf16 xr_l[96 * 66], xi_l[96 * 66];     // [k][p], rowlen 66 (conflict-free)
  __shared__ bf16 o1r_l[96 * 66], o1i_l[96 * 66];
  __shared__ __align__(16) float wch[2][16 * 96];   // streamed weight chunk (16 k-rows)
  const int n = blockIdx.y;
  const int m0 = blockIdx.x * 64;
  const int p = threadIdx.x & 63;
  const int v = threadIdx.x >> 6;
  const int oc0 = v * 24;

  // load X tile (bf16 into LDS)
  for (int idx = threadIdx.x; idx < 64 * 96; idx += 256) {
    int pp = idx / 96, k = idx % 96;
    int m = m0 + pp;
    int bh = m / 65, wf = m % 65;
    xr_l[k * 66 + pp] = __float2bfloat16(Xr[(size_t)m * 768 + n * 96 + k]);
    xi_l[k * 66 + pp] = __float2bfloat16(Xi[((size_t)bh * 128 + wf) * 768 + n * 96 + k]);
  }

  float ar[24], ai[24];
  // ================= layer 1 =================
  #pragma unroll
  for (int j = 0; j < 24; ++j) { ar[j] = 0.f; ai[j] = 0.f; }
  for (int kc = 0; kc < 6; ++kc) {
    __syncthreads();
    for (int idx = threadIdx.x; idx < 16 * 96; idx += 256) {
      int kk = idx / 96, oc = idx % 96;
      size_t off = ((size_t)n * 96 + kc * 16 + kk) * 96 + oc;
      wch[0][idx] = w1[off];
      wch[1][idx] = w1[73728 + off];
    }
    __syncthreads();
    for (int kk = 0; kk < 16; ++kk) {
      int kg = kc * 16 + kk;
      float xrv = __bfloat162float(xr_l[kg * 66 + p]);
      float xiv = __bfloat162float(xi_l[kg * 66 + p]);
      const float4* wr4 = (const float4*)(&wch[0][kk * 96 + oc0]);
      const float4* wi4 = (const float4*)(&wch[1][kk * 96 + oc0]);
      #pragma unroll
      for (int j = 0; j < 6; ++j) {
        float4 wr = wr4[j], wi = wi4[j];
        ar[4*j+0] += xrv * wr.x - xiv * wi.x;  ai[4*j+0] += xiv * wr.x + xrv * wi.x;
        ar[4*j+1] += xrv * wr.y - xiv * wi.y;  ai[4*j+1] += xiv * wr.y + xrv * wi.y;
        ar[4*j+2] += xrv * wr.z - xiv * wi.z;  ai[4*j+2] += xiv * wr.z + xrv * wi.z;
        ar[4*j+3] += xrv * wr.w - xiv * wi.w;  ai[4*j+3] += xiv * wr.w + xrv * wi.w;
      }
    }
  }
  // bias + exact gelu -> o1 LDS
  #pragma unroll
  for (int j = 0; j < 24; ++j) {
    int oc = oc0 + j;
    float vr = ar[j] + b1[n * 96 + oc];
    float vi = ai[j] + b1[768 + n * 96 + oc];
    vr = 0.5f * vr * (1.f + erff(vr * 0.70710678118654752f));
    vi = 0.5f * vi * (1.f + erff(vi * 0.70710678118654752f));
    o1r_l[oc * 66 + p] = __float2bfloat16(vr);
    o1i_l[oc * 66 + p] = __float2bfloat16(vi);
  }
  // ================= layer 2 =================
  #pragma unroll
  for (int j = 0; j < 24; ++j) { ar[j] = 0.f; ai[j] = 0.f; }
  for (int kc = 0; kc < 6; ++kc) {
    __syncthreads();   // also makes o1 stores visible before first read
    for (int idx = threadIdx.x; idx < 16 * 96; idx += 256) {
      int kk = idx / 96, oc = idx % 96;
      size_t off = ((size_t)n * 96 + kc * 16 + kk) * 96 + oc;
      wch[0][idx] = w2[off];
      wch[1][idx] = w2[73728 + off];
    }
    __syncthreads();
    for (int kk = 0; kk < 16; ++kk) {
      int kg = kc * 16 + kk;
      float xrv = __bfloat162float(o1r_l[kg * 66 + p]);
      float xiv = __bfloat162float(o1i_l[kg * 66 + p]);
      const float4* wr4 = (const float4*)(&wch[0][kk * 96 + oc0]);
      const float4* wi4 = (const float4*)(&wch[1][kk * 96 + oc0]);
      #pragma unroll
      for (int j = 0; j < 6; ++j) {
        float4 wr = wr4[j], wi = wi4[j];
        ar[4*j+0] += xrv * wr.x - xiv * wi.x;  ai[4*j+0] += xiv * wr.x + xrv * wi.x;
        ar[4*j+1] += xrv * wr.y - xiv * wi.y;  ai[4*j+1] += xiv * wr.y + xrv * wi.y;
        ar[4*j+2] += xrv * wr.z - xiv * wi.z;  ai[4*j+2] += xiv * wr.z + xrv * wi.z;
        ar[4*j+3] += xrv * wr.w - xiv * wi.w;  ai[4*j+3] += xiv * wr.w + xrv * wi.w;
      }
    }
  }
  // bias + softshrink -> stage into xr_l/xi_l (free now) -> coalesced global store
  __syncthreads();
  #pragma unroll
  for (int j = 0; j < 24; ++j) {
    int oc = oc0 + j;
    float vr = ar[j] + b2[n * 96 + oc];
    float vi = ai[j] + b2[768 + n * 96 + oc];
    vr = (vr > 0.01f) ? vr - 0.01f : ((vr < -0.01f) ? vr + 0.01f : 0.f);
    vi = (vi > 0.01f) ? vi - 0.01f : ((vi < -0.01f) ? vi + 0.01f : 0.f);
    xr_l[oc * 66 + p] = __float2bfloat16(vr);
    xi_l[oc * 66 + p] = __float2bfloat16(vi);
  }
  __syncthreads();
  for (int idx = threadIdx.x; idx < 64 * 96; idx += 256) {
    int pp = idx / 96, k = idx % 96;
    int m = m0 + pp;
    int bh = m / 65, wf = m % 65;
    Xr[(size_t)m * 768 + n * 96 + k] = __bfloat162float(xr_l[k * 66 + pp]);
    Xi[((size_t)bh * 128 + wf) * 768 + n * 96 + k] = __bfloat162float(xi_l[k * 66 + pp]);
  }
}

// ---- K5: inverse rFFT along W (hermitian extension), write real output in-place into d_out.
__global__ __launch_bounds__(256, 2) void k_ifftw(
    const float* __restrict__ Xr, float* io) {
  __shared__ float lr[128 * 64], li[128 * 64];
  const int bh = blockIdx.x;
  const int c0 = blockIdx.y * 64;
  const int c = threadIdx.x & 63;
  const int wq = threadIdx.x >> 6;
  // load half-spectrum slots 0..64 (li rows come from io's padded Xi region for this bh)
  for (int it = 0; it < 17; ++it) {
    int s = wq + (it << 2);
    if (s < 65) {
      lr[s * 64 + c] = Xr[((size_t)bh * 65 + s) * 768 + c0 + c];
      li[s * 64 + c] = io[((size_t)bh * 128 + s) * 768 + c0 + c];
    }
  }
  __syncthreads();
  // hermitian extension: full[s] = conj(full[128-s]) for s in 65..127
  for (int it = 0; it < 16; ++it) {
    int s = 65 + wq + (it << 2);
    if (s < 128) {
      lr[s * 64 + c] =  lr[(128 - s) * 64 + c];
      li[s * 64 + c] = -li[(128 - s) * 64 + c];
    }
  }
  fft128(lr, li, +1.f, c, wq);   // unnormalized inverse (1/128 applied in K4)
  #pragma unroll
  for (int it = 0; it < 32; ++it) {
    int slot = wq + (it << 2);
    int w = bitrev7(slot);
    io[((size_t)bh * 128 + w) * 768 + c0 + c] = lr[slot * 64 + c];  // real part only
  }
}

extern "C" void kernel_launch(void* const* d_in, const int* in_sizes, int n_in,
                              void* d_out, int out_size, void* d_ws, size_t ws_size,
                              hipStream_t stream) {
  const float* x  = (const float*)d_in[0];
  const float* w1 = (const float*)d_in[1];
  const float* b1 = (const float*)d_in[2];
  const float* w2 = (const float*)d_in[3];
  const float* b2 = (const float*)d_in[4];
  float* out = (float*)d_out;
  float* Xr = (float*)d_ws;   // [512, 65, 768] fp32 = 102 MB (real spectrum)
  float* Xi = out;            // padded [512, 128, 768], wf slots 0..64 used (imag spectrum)

  dim3 blk(256);
  k_fftw_fwd<<<dim3(512, 12), blk, 0, stream>>>(x, Xr, Xi);
  k_ffth   <<<dim3(260, 12), blk, 0, stream>>>(Xr, Xi, -1.f, 1.f);
  k_mlp    <<<dim3(520, 8),  blk, 0, stream>>>(Xr, Xi, w1, b1, w2, b2);
  k_ffth   <<<dim3(260, 12), blk, 0, stream>>>(Xr, Xi, +1.f, 1.f / 128.f);
  k_ifftw  <<<dim3(512, 12), blk, 0, stream>>>(Xr, out);
}

// Round 2
// 1056.337 us; speedup vs baseline: 1.6825x; 1.6825x over previous
//
#include <hip/hip_runtime.h>
#include <hip/hip_bf16.h>
#include <math.h>

typedef __bf16 bfx8 __attribute__((ext_vector_type(8)));
typedef __bf16 bfx4 __attribute__((ext_vector_type(4)));
typedef float f32x4 __attribute__((ext_vector_type(4)));

__device__ __forceinline__ int bitrev7(int x) {
  return ((x & 1) << 6) | ((x & 2) << 4) | ((x & 4) << 2) | (x & 8)
       | ((x & 16) >> 2) | ((x & 32) >> 4) | ((x & 64) >> 6);
}

// In-LDS 128-point complex FFT over 64 columns. lr/li layout: [slot*64 + col].
__device__ __forceinline__ void fft128(float* lr, float* li, float sign, int c, int wq) {
  const float base_ang = sign * (float)(2.0 * M_PI / 128.0);
  #pragma unroll
  for (int s = 0; s < 7; ++s) {
    int lh = 6 - s;
    int half = 1 << lh;
    __syncthreads();
    #pragma unroll
    for (int it = 0; it < 16; ++it) {
      int bf = wq + (it << 2);
      int j = bf & (half - 1);
      int blk = bf >> lh;
      int i1 = (blk << (lh + 1)) + j;
      int i2 = i1 + half;
      int k = j << s;
      float ar = lr[i1 * 64 + c], ai = li[i1 * 64 + c];
      float br = lr[i2 * 64 + c], bi = li[i2 * 64 + c];
      float sv, cv;
      __sincosf(base_ang * (float)k, &sv, &cv);
      float dr = ar - br, di = ai - bi;
      lr[i1 * 64 + c] = ar + br;
      li[i1 * 64 + c] = ai + bi;
      lr[i2 * 64 + c] = dr * cv - di * sv;
      li[i2 * 64 + c] = dr * sv + di * cv;
    }
  }
  __syncthreads();
}

// ---- K1: forward rFFT along W.
__global__ __launch_bounds__(256, 2) void k_fftw_fwd(
    const float* __restrict__ x, float* __restrict__ Xr, float* __restrict__ Xi) {
  __shared__ float lr[128 * 64], li[128 * 64];
  const int bh = blockIdx.x;
  const int c0 = blockIdx.y * 64;
  const int c = threadIdx.x & 63;
  const int wq = threadIdx.x >> 6;
  const float* xrow = x + (size_t)bh * (128 * 768) + c0 + c;
  #pragma unroll
  for (int it = 0; it < 32; ++it) {
    int w = wq + (it << 2);
    lr[w * 64 + c] = xrow[(size_t)w * 768];
    li[w * 64 + c] = 0.f;
  }
  fft128(lr, li, -1.f, c, wq);
  const float sc = 1.f / 128.f;
  #pragma unroll
  for (int it = 0; it < 32; ++it) {
    int slot = wq + (it << 2);
    int f = bitrev7(slot);
    if (f < 65) {
      Xr[((size_t)bh * 65 + f) * 768 + c0 + c]  = lr[slot * 64 + c] * sc;
      Xi[((size_t)bh * 128 + f) * 768 + c0 + c] = li[slot * 64 + c] * sc;
    }
  }
}

// ---- K2/K4: complex FFT along H, in-place per (b,wf) column.
__global__ __launch_bounds__(256, 2) void k_ffth(
    float* Xr, float* Xi, float sign, float scale) {
  __shared__ float lr[128 * 64], li[128 * 64];
  const int bw = blockIdx.x;
  const int b = bw / 65, wf = bw % 65;
  const int c0 = blockIdx.y * 64;
  const int c = threadIdx.x & 63;
  const int wq = threadIdx.x >> 6;
  const size_t baser = ((size_t)b * 128 * 65 + wf) * 768 + c0 + c;
  const size_t basei = ((size_t)b * 128 * 128 + wf) * 768 + c0 + c;
  #pragma unroll
  for (int it = 0; it < 32; ++it) {
    int h = wq + (it << 2);
    lr[h * 64 + c] = Xr[baser + (size_t)h * (65 * 768)];
    li[h * 64 + c] = Xi[basei + (size_t)h * (128 * 768)];
  }
  fft128(lr, li, sign, c, wq);
  #pragma unroll
  for (int it = 0; it < 32; ++it) {
    int slot = wq + (it << 2);
    int hf = bitrev7(slot);
    Xr[baser + (size_t)hf * (65 * 768)]  = lr[slot * 64 + c] * scale;
    Xi[basei + (size_t)hf * (128 * 768)] = li[slot * 64 + c] * scale;
  }
}

// ---- K3: block-diagonal complex MLP via bf16 MFMA. In-place on Xr/Xi.
// grid (520, 8): 64 positions x channel-block n per workgroup. 256 thr = 4 waves.
// Wave w computes rows [16w,16w+16) x all 96 out-channels (6 col tiles), r & i.
#define MP 104  // padded bf16 row length: 208 B rows (16B-aligned, 2-way banks = free)
__device__ __forceinline__ bfx8 neg8(bfx8 v) {
  union { bfx8 b; unsigned int u[4]; } t;
  t.b = v;
  t.u[0] ^= 0x80008000u; t.u[1] ^= 0x80008000u;
  t.u[2] ^= 0x80008000u; t.u[3] ^= 0x80008000u;
  return t.b;
}

__global__ __launch_bounds__(256, 2) void k_mlp(
    float* __restrict__ Xr, float* __restrict__ Xi,
    const float* __restrict__ w1, const float* __restrict__ b1,
    const float* __restrict__ w2, const float* __restrict__ b2) {
  __shared__ __align__(16) __bf16 Xl[2][64][MP];   // [r/i][m][k] activations (X, then O1)
  __shared__ __align__(16) __bf16 Wl[2][96][MP];   // [r/i][oc][k] weights (transposed)
  const int n = blockIdx.y;
  const int m0 = blockIdx.x * 64;
  const int tid = threadIdx.x;
  const int lane = tid & 63;
  const int w = tid >> 6;
  const int col = lane & 15;       // MFMA: A row / B col / C col
  const int quad = lane >> 4;      // MFMA: k-chunk / C row-group

  // stage X tile: fp32 global -> bf16 LDS [m][k]
  for (int e = tid; e < 64 * 24; e += 256) {
    int mm = e / 24, k4 = (e % 24) * 4;
    int m = m0 + mm;
    int bh = m / 65, wf = m - bh * 65;
    const float4 vr = *(const float4*)&Xr[(size_t)m * 768 + n * 96 + k4];
    const float4 vi = *(const float4*)&Xi[((size_t)bh * 128 + wf) * 768 + n * 96 + k4];
    bfx4 br = { (__bf16)vr.x, (__bf16)vr.y, (__bf16)vr.z, (__bf16)vr.w };
    bfx4 bi = { (__bf16)vi.x, (__bf16)vi.y, (__bf16)vi.z, (__bf16)vi.w };
    *(bfx4*)&Xl[0][mm][k4] = br;
    *(bfx4*)&Xl[1][mm][k4] = bi;
  }
  // stage W1: [k][oc] global -> [oc][k] LDS (bf16)
  for (int e = tid; e < 2 * 96 * 24; e += 256) {
    int ri = e / (96 * 24);
    int r = e - ri * (96 * 24);
    int kin = r / 24, oc4 = (r - kin * 24) * 4;
    const float4 v = *(const float4*)&w1[(size_t)ri * 73728 + ((size_t)n * 96 + kin) * 96 + oc4];
    Wl[ri][oc4 + 0][kin] = (__bf16)v.x;
    Wl[ri][oc4 + 1][kin] = (__bf16)v.y;
    Wl[ri][oc4 + 2][kin] = (__bf16)v.z;
    Wl[ri][oc4 + 3][kin] = (__bf16)v.w;
  }
  __syncthreads();

  const f32x4 fz = { 0.f, 0.f, 0.f, 0.f };
  f32x4 accR[6], accI[6];
  #pragma unroll
  for (int ct = 0; ct < 6; ++ct) { accR[ct] = fz; accI[ct] = fz; }

  // ============ layer 1 ============
  const int mrow = w * 16 + col;
  #pragma unroll
  for (int kc = 0; kc < 3; ++kc) {
    const int kb = kc * 32 + quad * 8;
    bfx8 axr = *(const bfx8*)&Xl[0][mrow][kb];
    bfx8 axi = *(const bfx8*)&Xl[1][mrow][kb];
    bfx8 axin = neg8(axi);
    #pragma unroll
    for (int ct = 0; ct < 6; ++ct) {
      bfx8 bwr = *(const bfx8*)&Wl[0][ct * 16 + col][kb];
      bfx8 bwi = *(const bfx8*)&Wl[1][ct * 16 + col][kb];
      accR[ct] = __builtin_amdgcn_mfma_f32_16x16x32_bf16(axr,  bwr, accR[ct], 0, 0, 0);
      accR[ct] = __builtin_amdgcn_mfma_f32_16x16x32_bf16(axin, bwi, accR[ct], 0, 0, 0);
      accI[ct] = __builtin_amdgcn_mfma_f32_16x16x32_bf16(axi,  bwr, accI[ct], 0, 0, 0);
      accI[ct] = __builtin_amdgcn_mfma_f32_16x16x32_bf16(axr,  bwi, accI[ct], 0, 0, 0);
    }
  }
  __syncthreads();   // all waves done reading Xl/Wl for layer 1

  // epilogue 1: bias + exact GELU -> bf16 O1 into Xl; stage W2 into Wl
  #pragma unroll
  for (int ct = 0; ct < 6; ++ct) {
    int oc = ct * 16 + col;
    float br = b1[n * 96 + oc];
    float bi = b1[768 + n * 96 + oc];
    int mbase = w * 16 + quad * 4;
    #pragma unroll
    for (int r = 0; r < 4; ++r) {
      float vr = accR[ct][r] + br;
      float vi = accI[ct][r] + bi;
      vr = 0.5f * vr * (1.f + erff(vr * 0.70710678118654752f));
      vi = 0.5f * vi * (1.f + erff(vi * 0.70710678118654752f));
      Xl[0][mbase + r][oc] = (__bf16)vr;
      Xl[1][mbase + r][oc] = (__bf16)vi;
    }
  }
  for (int e = tid; e < 2 * 96 * 24; e += 256) {
    int ri = e / (96 * 24);
    int r = e - ri * (96 * 24);
    int kin = r / 24, oc4 = (r - kin * 24) * 4;
    const float4 v = *(const float4*)&w2[(size_t)ri * 73728 + ((size_t)n * 96 + kin) * 96 + oc4];
    Wl[ri][oc4 + 0][kin] = (__bf16)v.x;
    Wl[ri][oc4 + 1][kin] = (__bf16)v.y;
    Wl[ri][oc4 + 2][kin] = (__bf16)v.z;
    Wl[ri][oc4 + 3][kin] = (__bf16)v.w;
  }
  __syncthreads();

  // ============ layer 2 ============
  #pragma unroll
  for (int ct = 0; ct < 6; ++ct) { accR[ct] = fz; accI[ct] = fz; }
  #pragma unroll
  for (int kc = 0; kc < 3; ++kc) {
    const int kb = kc * 32 + quad * 8;
    bfx8 axr = *(const bfx8*)&Xl[0][mrow][kb];
    bfx8 axi = *(const bfx8*)&Xl[1][mrow][kb];
    bfx8 axin = neg8(axi);
    #pragma unroll
    for (int ct = 0; ct < 6; ++ct) {
      bfx8 bwr = *(const bfx8*)&Wl[0][ct * 16 + col][kb];
      bfx8 bwi = *(const bfx8*)&Wl[1][ct * 16 + col][kb];
      accR[ct] = __builtin_amdgcn_mfma_f32_16x16x32_bf16(axr,  bwr, accR[ct], 0, 0, 0);
      accR[ct] = __builtin_amdgcn_mfma_f32_16x16x32_bf16(axin, bwi, accR[ct], 0, 0, 0);
      accI[ct] = __builtin_amdgcn_mfma_f32_16x16x32_bf16(axi,  bwr, accI[ct], 0, 0, 0);
      accI[ct] = __builtin_amdgcn_mfma_f32_16x16x32_bf16(axr,  bwi, accI[ct], 0, 0, 0);
    }
  }

  // epilogue 2: bias + softshrink, fp32 store to global (in-place)
  #pragma unroll
  for (int ct = 0; ct < 6; ++ct) {
    int oc = ct * 16 + col;
    float br = b2[n * 96 + oc];
    float bi = b2[768 + n * 96 + oc];
    #pragma unroll
    for (int r = 0; r < 4; ++r) {
      int m = m0 + w * 16 + quad * 4 + r;
      int bh = m / 65, wf = m - bh * 65;
      float vr = accR[ct][r] + br;
      float vi = accI[ct][r] + bi;
      vr = (vr > 0.01f) ? vr - 0.01f : ((vr < -0.01f) ? vr + 0.01f : 0.f);
      vi = (vi > 0.01f) ? vi - 0.01f : ((vi < -0.01f) ? vi + 0.01f : 0.f);
      Xr[(size_t)m * 768 + n * 96 + oc] = vr;
      Xi[((size_t)bh * 128 + wf) * 768 + n * 96 + oc] = vi;
    }
  }
}

// ---- K5: inverse rFFT along W (hermitian extension), write real output into d_out.
__global__ __launch_bounds__(256, 2) void k_ifftw(
    const float* __restrict__ Xr, float* io) {
  __shared__ float lr[128 * 64], li[128 * 64];
  const int bh = blockIdx.x;
  const int c0 = blockIdx.y * 64;
  const int c = threadIdx.x & 63;
  const int wq = threadIdx.x >> 6;
  for (int it = 0; it < 17; ++it) {
    int s = wq + (it << 2);
    if (s < 65) {
      lr[s * 64 + c] = Xr[((size_t)bh * 65 + s) * 768 + c0 + c];
      li[s * 64 + c] = io[((size_t)bh * 128 + s) * 768 + c0 + c];
    }
  }
  __syncthreads();
  for (int it = 0; it < 16; ++it) {
    int s = 65 + wq + (it << 2);
    if (s < 128) {
      lr[s * 64 + c] =  lr[(128 - s) * 64 + c];
      li[s * 64 + c] = -li[(128 - s) * 64 + c];
    }
  }
  fft128(lr, li, +1.f, c, wq);
  #pragma unroll
  for (int it = 0; it < 32; ++it) {
    int slot = wq + (it << 2);
    int w = bitrev7(slot);
    io[((size_t)bh * 128 + w) * 768 + c0 + c] = lr[slot * 64 + c];
  }
}

extern "C" void kernel_launch(void* const* d_in, const int* in_sizes, int n_in,
                              void* d_out, int out_size, void* d_ws, size_t ws_size,
                              hipStream_t stream) {
  const float* x  = (const float*)d_in[0];
  const float* w1 = (const float*)d_in[1];
  const float* b1 = (const float*)d_in[2];
  const float* w2 = (const float*)d_in[3];
  const float* b2 = (const float*)d_in[4];
  float* out = (float*)d_out;
  float* Xr = (float*)d_ws;   // [512, 65, 768] fp32 (real spectrum)
  float* Xi = out;            // padded [512, 128, 768], wf slots 0..64 (imag spectrum)

  dim3 blk(256);
  k_fftw_fwd<<<dim3(512, 12), blk, 0, stream>>>(x, Xr, Xi);
  k_ffth   <<<dim3(260, 12), blk, 0, stream>>>(Xr, Xi, -1.f, 1.f);
  k_mlp    <<<dim3(520, 8),  blk, 0, stream>>>(Xr, Xi, w1, b1, w2, b2);
  k_ffth   <<<dim3(260, 12), blk, 0, stream>>>(Xr, Xi, +1.f, 1.f / 128.f);
  k_ifftw  <<<dim3(512, 12), blk, 0, stream>>>(Xr, out);
}